// Round 5
// baseline (8202.748 us; speedup 1.0000x reference)
//
#include <hip/hip_runtime.h>
#include <hip/hip_cooperative_groups.h>
#include <cfloat>
#include <cmath>

namespace cg = cooperative_groups;

#define NB 128
#define NL 48
#define HID 512
#define NSLOT 48
#define NN 2560              // 5*HID output cols
#define NNODE (NB*NSLOT)     // 6144
#define AROWS (NB*(NL-1))    // 6016 phase-A pair rows
#define SROWS (NB*2)         // 256 per-step refresh pairs
#define LGRID 640            // cooperative grid: 4 m-tiles x 160 n-tiles

// ---------------- workspace layout (float units) ----------------
static const size_t offH    = 0;                                   // [B][48][512]
static const size_t offC    = offH  + (size_t)NNODE*HID;
static const size_t offCH   = offC  + (size_t)NNODE*HID;           // candidate h
static const size_t offCC   = offCH + (size_t)NNODE*HID;           // candidate c
static const size_t offLG   = offCC + (size_t)NNODE*HID;           // logits [B][48]
static const size_t offNXT  = offLG  + NNODE;                      // int
static const size_t offPRV  = offNXT + NNODE;                      // int
static const size_t offROWS = offPRV + NNODE;                      // int4 x 256
static const size_t offROWSA= offROWS + (size_t)4*SROWS;           // int4 x 6016
static const size_t offROWSN= offROWSA + (size_t)4*AROWS;          // int x 6144
static const size_t offPROW = offROWSN + NNODE;                    // int x 128
static const size_t offBIG  = offPROW + 128;                       // PL, PR (NNODE*NN each)

__device__ __forceinline__ float sigf(float x){ return 1.0f/(1.0f+expf(-x)); }

// ---------------- init: copy input -> H,C ; init links/logits ----------------
__global__ void k_init(const float* __restrict__ in, const int* __restrict__ len,
                       float* __restrict__ H, float* __restrict__ Cc,
                       float* __restrict__ LG, int* __restrict__ NXT,
                       int* __restrict__ PRV, int4* __restrict__ ROWS)
{
    int bs = blockIdx.x;            // b*48+s
    int b  = bs / NSLOT, s = bs % NSLOT;
    int t  = threadIdx.x;           // 256 threads, 1 float4 each
    const float4* inrow = (const float4*)(in + (size_t)bs*2*HID);
    float4 v = inrow[t];
    if (t < 128) ((float4*)(H  + (size_t)bs*HID))[t]       = v;
    else         ((float4*)(Cc + (size_t)bs*HID))[t - 128] = v;
    if (t == 0) {
        int lb = len[b];
        NXT[bs] = (s+1 < lb) ? s+1 : -1;
        PRV[bs] = (s > 0 && s < lb) ? s-1 : -1;
        LG[bs]  = -FLT_MAX;
        if (s == 0) {
            ROWS[b*2+0] = make_int4(0,0,0,-1);
            ROWS[b*2+1] = make_int4(0,0,0,-1);
        }
    }
}

// ---------------- descriptors: pair rows (phase A) + node rows ----------------
__global__ void k_descA(const int* __restrict__ len, int4* __restrict__ ROWSA,
                        int* __restrict__ ROWSN)
{
    int r = blockIdx.x*256 + threadIdx.x;
    if (r < NNODE) ROWSN[r] = r;
    if (r >= AROWS) return;
    int b = r/(NL-1), s = r%(NL-1);
    int lb = len[b];
    ROWSA[r] = make_int4(b, s, s+1, (s <= lb-2) ? s : -1);
}

// ================= split-W product GEMM (direct write to PL/PR) =================
// PL[node][n] = sum_k H[node][k]*W[n][k],  PR[node][n] = sum_k H[node][k]*W[n][512+k]
template<int MI, int KT>
__global__ __launch_bounds__(256, 4)
void k_gemmP(const int* __restrict__ rows,
             const float* __restrict__ H, const float* __restrict__ W,
             float* __restrict__ PL, float* __restrict__ PR)
{
    constexpr int BM  = 16*MI;
    constexpr int AF4 = BM/64;
    constexpr int LDA = BM + 4;
    constexpr int LDB = 68;
    __shared__ float As[2][16*LDA];
    __shared__ float Bs[2][16*LDB];

    const int t   = threadIdx.x;
    const int m0  = blockIdx.x*BM;
    const int vn0 = blockIdx.y*64;
    const int side = (vn0 >= NN);
    const int n0  = side ? vn0 - NN : vn0;
    float* OUT = side ? PR : PL;

    int aoff[AF4], arow[AF4], aseg[AF4];
    #pragma unroll
    for (int j=0;j<AF4;++j){
        int f = t*AF4 + j;
        arow[j] = f >> 2; aseg[j] = f & 3;
        aoff[j] = rows[m0 + arow[j]]*HID + aseg[j]*4;
    }
    const int brow = t >> 2, bseg = t & 3;
    const float* wptr = W + (size_t)(n0 + brow)*1024 + side*HID + bseg*4;

    const int tm = t >> 4, tn = t & 15;

    float acc[MI][4];
    #pragma unroll
    for (int mi=0;mi<MI;++mi)
        #pragma unroll
        for (int j=0;j<4;++j) acc[mi][j]=0.f;

    float4 av[AF4], bv;
    auto gload = [&](int kt){
        int kg = kt*16;
        #pragma unroll
        for (int j=0;j<AF4;++j) av[j] = *(const float4*)(H + aoff[j] + kg);
        bv = *(const float4*)(wptr + kg);
    };
    auto swrite = [&](int buf){
        #pragma unroll
        for (int j=0;j<AF4;++j){
            As[buf][(aseg[j]*4+0)*LDA + arow[j]] = av[j].x;
            As[buf][(aseg[j]*4+1)*LDA + arow[j]] = av[j].y;
            As[buf][(aseg[j]*4+2)*LDA + arow[j]] = av[j].z;
            As[buf][(aseg[j]*4+3)*LDA + arow[j]] = av[j].w;
        }
        Bs[buf][(bseg*4+0)*LDB + brow] = bv.x;
        Bs[buf][(bseg*4+1)*LDB + brow] = bv.y;
        Bs[buf][(bseg*4+2)*LDB + brow] = bv.z;
        Bs[buf][(bseg*4+3)*LDB + brow] = bv.w;
    };

    gload(0); swrite(0); __syncthreads();

    for (int kt=0; kt<KT; ++kt){
        int buf = kt & 1;
        if (kt+1 < KT) gload(kt+1);
        #pragma unroll
        for (int k=0;k<16;++k){
            float a[MI];
            #pragma unroll
            for (int mi=0;mi<MI;mi+=4){
                float4 a4 = *(const float4*)&As[buf][k*LDA + tm*MI + mi];
                a[mi]=a4.x; a[mi+1]=a4.y; a[mi+2]=a4.z; a[mi+3]=a4.w;
            }
            float4 b4 = *(const float4*)&Bs[buf][k*LDB + tn*4];
            #pragma unroll
            for (int mi=0;mi<MI;++mi){
                acc[mi][0] = fmaf(a[mi], b4.x, acc[mi][0]);
                acc[mi][1] = fmaf(a[mi], b4.y, acc[mi][1]);
                acc[mi][2] = fmaf(a[mi], b4.z, acc[mi][2]);
                acc[mi][3] = fmaf(a[mi], b4.w, acc[mi][3]);
            }
        }
        if (kt+1 < KT) swrite(buf^1);
        __syncthreads();
    }

    #pragma unroll
    for (int mi=0;mi<MI;++mi){
        int row = m0 + tm*MI + mi;
        float4 o; o.x=acc[mi][0]; o.y=acc[mi][1]; o.z=acc[mi][2]; o.w=acc[mi][3];
        *(float4*)(OUT + (size_t)rows[row]*NN + n0 + tn*4) = o;
    }
}

// ---------------- phase-A combine: v = PL[l]+PR[r]+bias -> gates -> CH/CC + logit ----------------
__global__ void k_combineP(const int4* __restrict__ rows,
                           const float* __restrict__ PL, const float* __restrict__ PR,
                           const float* __restrict__ Cc, const float* __restrict__ bias,
                           const float* __restrict__ q,
                           float* __restrict__ CH, float* __restrict__ CC,
                           float* __restrict__ LG)
{
    int4 rd = rows[blockIdx.x];
    if (rd.w < 0) return;
    int t = threadIdx.x;
    int b = rd.x, sl = rd.y, sr = rd.z, dst = rd.w;
    const float* pl = PL + (size_t)(b*NSLOT+sl)*NN;
    const float* pr = PR + (size_t)(b*NSLOT+sr)*NN;
    const float* cl = Cc + (size_t)(b*NSLOT+sl)*HID;
    const float* cr = Cc + (size_t)(b*NSLOT+sr)*HID;
    float part = 0.f;
    #pragma unroll
    for (int h2=0; h2<2; ++h2){
        int c = t + h2*256;
        float v[5];
        #pragma unroll
        for (int g=0; g<5; ++g)
            v[g] = pl[g*HID+c] + pr[g*HID+c] + bias[g*HID+c];
        float cn = cl[c]*sigf(v[1]+1.f) + cr[c]*sigf(v[2]+1.f) + tanhf(v[3])*sigf(v[0]);
        float hn = sigf(v[4])*tanhf(cn);
        CH[(size_t)(b*NSLOT+dst)*HID + c] = hn;
        CC[(size_t)(b*NSLOT+dst)*HID + c] = cn;
        part += q[c]*hn;
    }
    __shared__ float red[4];
    #pragma unroll
    for (int off=32; off; off>>=1) part += __shfl_xor(part, off);
    if ((t & 63) == 0) red[t>>6] = part;
    __syncthreads();
    if (t == 0) LG[b*NSLOT + dst] = red[0]+red[1]+red[2]+red[3];
}

// ================= cooperative whole-loop kernel =================
// grid = 640 blocks x 256 threads. Per step:
//   GEMM (all blocks): products of the 128 new nodes, BM=32 x BN=32, K=512
//   grid.sync()
//   combine+argmax+commit+relink (blocks 0..127, one per batch)
//   grid.sync()
__global__ __launch_bounds__(256, 4)
void k_loop(const int* __restrict__ len,
            float* __restrict__ H, float* __restrict__ Cc,
            float* __restrict__ CH, float* __restrict__ CC,
            float* __restrict__ LG, int* __restrict__ NXT, int* __restrict__ PRV,
            int4* __restrict__ ROWS, int* __restrict__ PROW,
            float* __restrict__ PL, float* __restrict__ PR,
            const float* __restrict__ W, const float* __restrict__ bias,
            const float* __restrict__ q, float* __restrict__ out)
{
    cg::grid_group grid = cg::this_grid();
    const int bid = blockIdx.x, t = threadIdx.x;

    __shared__ float As[2*16*36];
    __shared__ float Bs[2*16*36];
    __shared__ float slg[NSLOT];
    __shared__ float red[8];
    __shared__ int   ss[1];

    // ---- step 0: argmax on phase-A logits, commit, relink ----
    if (bid < NB){
        int b = bid, base = b*NSLOT;
        if (t < 64){
            float val = (t < NSLOT)? LG[base+t] : -FLT_MAX;
            int idx = t;
            for (int off=1; off<64; off<<=1){
                float ov=__shfl_xor(val,off); int oi=__shfl_xor(idx,off);
                if (ov>val || (ov==val && oi<idx)){ val=ov; idx=oi; }
            }
            if (t==0) ss[0]=idx;
        }
        __syncthreads();
        int sstar = ss[0];
        {
            const float4* sh = (const float4*)(CH + (size_t)(base+sstar)*HID);
            const float4* sc = (const float4*)(CC + (size_t)(base+sstar)*HID);
            float4* dh = (float4*)(H  + (size_t)(base+sstar)*HID);
            float4* dc = (float4*)(Cc + (size_t)(base+sstar)*HID);
            if (t < 128) dh[t] = sh[t];
            else         dc[t-128] = sc[t-128];
        }
        if (t == 0){
            int r  = NXT[base+sstar];
            int qn = NXT[base+r];
            int p  = PRV[base+sstar];
            NXT[base+sstar] = qn;
            if (qn >= 0) PRV[base+qn] = sstar;
            LG[base+r] = -FLT_MAX;
            if (qn < 0) LG[base+sstar] = -FLT_MAX;
            ROWS[b*2+0] = (p  >= 0) ? make_int4(b, p, sstar, p)      : make_int4(0,0,0,-1);
            ROWS[b*2+1] = (qn >= 0) ? make_int4(b, sstar, qn, sstar) : make_int4(0,0,0,-1);
            PROW[b] = base + sstar;
        }
    }
    grid.sync();

    for (int i = 1; i < NL-1; ++i){
        // ===== GEMM: PL/PR of each batch's new node =====
        {
            const int m    = bid & 3;
            const int nt   = bid >> 2;
            const int side = (nt >= 80) ? 1 : 0;
            const int n0   = (nt - side*80)*32;
            float* OUT = side ? PR : PL;

            const bool isA = (t < 128);
            const int l = t & 127;
            const int srow = l >> 2, sseg = l & 3;
            const float* gptr;
            if (isA) gptr = H + (size_t)PROW[m*32 + srow]*HID + sseg*4;
            else     gptr = W + (size_t)(n0 + srow)*1024 + side*HID + sseg*4;
            float* S = isA ? As : Bs;

            const int tm = t >> 4, tn = t & 15;
            float a00=0.f, a01=0.f, a10=0.f, a11=0.f;

            float4 v = *(const float4*)gptr;
            auto sw = [&](int buf){
                float* p = S + buf*(16*36);
                p[(sseg*4+0)*36 + srow] = v.x;
                p[(sseg*4+1)*36 + srow] = v.y;
                p[(sseg*4+2)*36 + srow] = v.z;
                p[(sseg*4+3)*36 + srow] = v.w;
            };
            sw(0);
            __syncthreads();
            for (int kt=0; kt<32; ++kt){
                int buf = kt & 1;
                if (kt+1 < 32) v = *(const float4*)(gptr + (kt+1)*16);
                const float* pa = As + buf*(16*36);
                const float* pb = Bs + buf*(16*36);
                #pragma unroll
                for (int k=0;k<16;++k){
                    float2 a2 = *(const float2*)(pa + k*36 + tm*2);
                    float2 b2 = *(const float2*)(pb + k*36 + tn*2);
                    a00 = fmaf(a2.x, b2.x, a00);
                    a01 = fmaf(a2.x, b2.y, a01);
                    a10 = fmaf(a2.y, b2.x, a10);
                    a11 = fmaf(a2.y, b2.y, a11);
                }
                if (kt+1 < 32) sw(buf^1);
                __syncthreads();
            }
            {
                int node0 = PROW[m*32 + tm*2 + 0];
                int node1 = PROW[m*32 + tm*2 + 1];
                float2 o0; o0.x=a00; o0.y=a01;
                float2 o1; o1.x=a10; o1.y=a11;
                *(float2*)(OUT + (size_t)node0*NN + n0 + tn*2) = o0;
                *(float2*)(OUT + (size_t)node1*NN + n0 + tn*2) = o1;
            }
        }
        grid.sync();

        // ===== combine + argmax + commit + relink (one block per batch) =====
        if (bid < NB){
            int b = bid, base = b*NSLOT;
            int4 r0 = ROWS[b*2+0], r1 = ROWS[b*2+1];
            bool v0 = (r0.w >= 0), v1 = (r1.w >= 0);
            int node = PROW[b];

            float plnew[10], prnew[10];
            if (v0 || v1){
                #pragma unroll
                for (int j=0;j<10;++j){
                    int c = j*256 + t;
                    plnew[j] = PL[(size_t)node*NN + c];
                    prnew[j] = PR[(size_t)node*NN + c];
                }
            }
            for (int e=0; e<2; ++e){
                int4 rd = e ? r1 : r0;
                bool valid = e ? v1 : v0;
                float part = 0.f;
                if (valid){
                    const float* OTH = e ? (PR + (size_t)(base+rd.z)*NN)
                                         : (PL + (size_t)(base+rd.y)*NN);
                    const float* cl = Cc + (size_t)(base+rd.y)*HID;
                    const float* cr = Cc + (size_t)(base+rd.z)*HID;
                    int dst = rd.w;
                    #pragma unroll
                    for (int h2=0; h2<2; ++h2){
                        int c = t + h2*256;
                        float v[5];
                        #pragma unroll
                        for (int g=0; g<5; ++g){
                            int j = g*2 + h2;
                            float mine = e ? plnew[j] : prnew[j];
                            v[g] = OTH[g*HID + c] + mine + bias[g*HID + c];
                        }
                        float cn = cl[c]*sigf(v[1]+1.f) + cr[c]*sigf(v[2]+1.f) + tanhf(v[3])*sigf(v[0]);
                        float hn = sigf(v[4])*tanhf(cn);
                        CH[(size_t)(base+dst)*HID + c] = hn;
                        CC[(size_t)(base+dst)*HID + c] = cn;
                        part += q[c]*hn;
                    }
                }
                #pragma unroll
                for (int off=32; off; off>>=1) part += __shfl_xor(part, off);
                if ((t & 63) == 0) red[e*4 + (t>>6)] = part;
            }
            if (t < NSLOT) slg[t] = LG[base+t];
            __syncthreads();
            if (t == 0){
                float s0 = red[0]+red[1]+red[2]+red[3];
                float s1 = red[4]+red[5]+red[6]+red[7];
                if (v0){ LG[base+r0.w]=s0; slg[r0.w]=s0; }
                if (v1){ LG[base+r1.w]=s1; slg[r1.w]=s1; }
            }
            __syncthreads();

            int lb = len[b];
            if (i > lb-2){
                if (t==0){
                    ROWS[b*2+0]=make_int4(0,0,0,-1);
                    ROWS[b*2+1]=make_int4(0,0,0,-1);
                    PROW[b]=base;
                }
            } else {
                if (t < 64){
                    float val = (t < NSLOT)? slg[t] : -FLT_MAX;
                    int idx = t;
                    for (int off=1; off<64; off<<=1){
                        float ov=__shfl_xor(val,off); int oi=__shfl_xor(idx,off);
                        if (ov>val || (ov==val && oi<idx)){ val=ov; idx=oi; }
                    }
                    if (t==0) ss[0]=idx;
                }
                __syncthreads();
                int sstar = ss[0];
                {
                    const float4* sh = (const float4*)(CH + (size_t)(base+sstar)*HID);
                    const float4* sc = (const float4*)(CC + (size_t)(base+sstar)*HID);
                    float4* dh = (float4*)(H  + (size_t)(base+sstar)*HID);
                    float4* dc = (float4*)(Cc + (size_t)(base+sstar)*HID);
                    if (t < 128) dh[t] = sh[t];
                    else         dc[t-128] = sc[t-128];
                }
                if (t == 0){
                    int r  = NXT[base+sstar];
                    int qn = NXT[base+r];
                    int p  = PRV[base+sstar];
                    NXT[base+sstar] = qn;
                    if (qn >= 0) PRV[base+qn] = sstar;
                    LG[base+r] = -FLT_MAX;
                    if (qn < 0) LG[base+sstar] = -FLT_MAX;
                    ROWS[b*2+0] = (p  >= 0) ? make_int4(b, p, sstar, p)      : make_int4(0,0,0,-1);
                    ROWS[b*2+1] = (qn >= 0) ? make_int4(b, sstar, qn, sstar) : make_int4(0,0,0,-1);
                    PROW[b] = base + sstar;
                }
            }
        }
        grid.sync();
    }

    // ---- output: root = slot 0 ----
    if (bid < NB && t < 128)
        ((float4*)out)[bid*128 + t] = ((const float4*)(H + (size_t)bid*NSLOT*HID))[t];
}

// ================= fallback per-step kernels (round-3/4 path) =================
__global__ void k_step0(const int* __restrict__ len,
                        float* __restrict__ H, float* __restrict__ Cc,
                        const float* __restrict__ CH, const float* __restrict__ CC,
                        float* __restrict__ LG, int* __restrict__ NXT,
                        int* __restrict__ PRV, int4* __restrict__ ROWS,
                        int* __restrict__ PROW)
{
    int b = blockIdx.x, lane = threadIdx.x;   // block = 64 = 1 wave
    int base = b*NSLOT;

    float val = (lane < NSLOT) ? LG[base+lane] : -FLT_MAX;
    int idx = lane;
    for (int off=1; off<64; off<<=1){
        float oval = __shfl_xor(val, off);
        int   oidx = __shfl_xor(idx, off);
        if (oval > val || (oval == val && oidx < idx)){ val = oval; idx = oidx; }
    }
    int sstar = idx;
    int r  = NXT[base+sstar];
    int qn = NXT[base+r];
    int p  = PRV[base+sstar];

    const float4* sh = (const float4*)(CH + (size_t)(base+sstar)*HID);
    const float4* sc = (const float4*)(CC + (size_t)(base+sstar)*HID);
    float4* dh = (float4*)(H  + (size_t)(base+sstar)*HID);
    float4* dc = (float4*)(Cc + (size_t)(base+sstar)*HID);
    dh[lane] = sh[lane]; dh[lane+64] = sh[lane+64];
    dc[lane] = sc[lane]; dc[lane+64] = sc[lane+64];

    if (lane==0){
        NXT[base+sstar] = qn;
        if (qn >= 0) PRV[base+qn] = sstar;
        LG[base+r] = -FLT_MAX;
        if (qn < 0) LG[base+sstar] = -FLT_MAX;
        ROWS[b*2+0] = (p  >= 0) ? make_int4(b, p, sstar, p)      : make_int4(0,0,0,-1);
        ROWS[b*2+1] = (qn >= 0) ? make_int4(b, sstar, qn, sstar) : make_int4(0,0,0,-1);
        PROW[b] = base + sstar;
    }
}

__global__ __launch_bounds__(256, 4)
void k_combineStep(int i, const int* __restrict__ len,
                   float* __restrict__ PL, float* __restrict__ PR,
                   int4* __restrict__ ROWS, int* __restrict__ PROW,
                   float* __restrict__ H, float* __restrict__ Cc,
                   float* __restrict__ CH, float* __restrict__ CC,
                   float* __restrict__ LG, int* __restrict__ NXT,
                   int* __restrict__ PRV,
                   const float* __restrict__ bias, const float* __restrict__ q)
{
    int b = blockIdx.x, t = threadIdx.x;
    int base = b*NSLOT;
    int4 r0 = ROWS[b*2+0], r1 = ROWS[b*2+1];
    bool v0 = (r0.w >= 0), v1 = (r1.w >= 0);
    int node = PROW[b];
    __shared__ float slg[NSLOT];
    __shared__ float red[8];
    __shared__ int ss[1];

    float plnew[10], prnew[10];
    if (v0 || v1){
        #pragma unroll
        for (int j=0;j<10;++j){
            int c = j*256 + t;
            plnew[j] = PL[(size_t)node*NN + c];
            prnew[j] = PR[(size_t)node*NN + c];
        }
    }
    for (int e=0; e<2; ++e){
        int4 rd = e ? r1 : r0;
        bool valid = e ? v1 : v0;
        float part = 0.f;
        if (valid){
            const float* OTH = e ? (PR + (size_t)(base+rd.z)*NN)
                                 : (PL + (size_t)(base+rd.y)*NN);
            const float* cl = Cc + (size_t)(base+rd.y)*HID;
            const float* cr = Cc + (size_t)(base+rd.z)*HID;
            int dst = rd.w;
            #pragma unroll
            for (int h2=0; h2<2; ++h2){
                int c = t + h2*256;
                float v[5];
                #pragma unroll
                for (int g=0; g<5; ++g){
                    int j = g*2 + h2;
                    float mine = e ? plnew[j] : prnew[j];
                    v[g] = OTH[g*HID + c] + mine + bias[g*HID + c];
                }
                float cn = cl[c]*sigf(v[1]+1.f) + cr[c]*sigf(v[2]+1.f) + tanhf(v[3])*sigf(v[0]);
                float hn = sigf(v[4])*tanhf(cn);
                CH[(size_t)(base+dst)*HID + c] = hn;
                CC[(size_t)(base+dst)*HID + c] = cn;
                part += q[c]*hn;
            }
        }
        #pragma unroll
        for (int off=32; off; off>>=1) part += __shfl_xor(part, off);
        if ((t & 63) == 0) red[e*4 + (t>>6)] = part;
    }
    if (t < NSLOT) slg[t] = LG[base+t];
    __syncthreads();
    if (t == 0){
        float s0 = red[0]+red[1]+red[2]+red[3];
        float s1 = red[4]+red[5]+red[6]+red[7];
        if (v0){ LG[base+r0.w]=s0; slg[r0.w]=s0; }
        if (v1){ LG[base+r1.w]=s1; slg[r1.w]=s1; }
    }
    __syncthreads();

    int lb = len[b];
    if (i > lb-2){
        if (t==0){
            ROWS[b*2+0]=make_int4(0,0,0,-1);
            ROWS[b*2+1]=make_int4(0,0,0,-1);
            PROW[b]=base;
        }
        return;
    }

    if (t < 64){
        float val = (t < NSLOT)? slg[t] : -FLT_MAX;
        int idx = t;
        for (int off=1; off<64; off<<=1){
            float ov=__shfl_xor(val,off); int oi=__shfl_xor(idx,off);
            if (ov>val || (ov==val && oi<idx)){ val=ov; idx=oi; }
        }
        if (t==0) ss[0]=idx;
    }
    __syncthreads();
    int sstar = ss[0];
    {
        const float4* sh = (const float4*)(CH + (size_t)(base+sstar)*HID);
        const float4* sc = (const float4*)(CC + (size_t)(base+sstar)*HID);
        float4* dh = (float4*)(H  + (size_t)(base+sstar)*HID);
        float4* dc = (float4*)(Cc + (size_t)(base+sstar)*HID);
        if (t < 128) dh[t] = sh[t];
        else         dc[t-128] = sc[t-128];
    }
    if (t == 0){
        int r  = NXT[base+sstar];
        int qn = NXT[base+r];
        int p  = PRV[base+sstar];
        NXT[base+sstar] = qn;
        if (qn >= 0) PRV[base+qn] = sstar;
        LG[base+r] = -FLT_MAX;
        if (qn < 0) LG[base+sstar] = -FLT_MAX;
        ROWS[b*2+0] = (p  >= 0) ? make_int4(b, p, sstar, p)      : make_int4(0,0,0,-1);
        ROWS[b*2+1] = (qn >= 0) ? make_int4(b, sstar, qn, sstar) : make_int4(0,0,0,-1);
        PROW[b] = base + sstar;
    }
}

// ---------------- output: root = slot 0 (fallback) ----------------
__global__ void k_out(const float* __restrict__ H, float* __restrict__ out)
{
    int b = blockIdx.x, t = threadIdx.x;       // 128 threads x float4
    ((float4*)out)[b*128 + t] = ((const float4*)(H + (size_t)b*NSLOT*HID))[t];
}

extern "C" void kernel_launch(void* const* d_in, const int* in_sizes, int n_in,
                              void* d_out, int out_size, void* d_ws, size_t ws_size,
                              hipStream_t stream)
{
    const float* in   = (const float*)d_in[0];
    const float* W    = (const float*)d_in[1];
    const float* bias = (const float*)d_in[2];
    const float* q    = (const float*)d_in[3];
    const int*   len  = (const int*)d_in[4];

    float* ws = (float*)d_ws;
    float* H  = ws + offH;
    float* Cc = ws + offC;
    float* CH = ws + offCH;
    float* CC = ws + offCC;
    float* LG = ws + offLG;
    int* NXT  = (int*)(ws + offNXT);
    int* PRV  = (int*)(ws + offPRV);
    int4* ROWS  = (int4*)(ws + offROWS);
    int4* ROWSA = (int4*)(ws + offROWSA);
    int*  ROWSN = (int*)(ws + offROWSN);
    int*  PROW  = (int*)(ws + offPROW);
    float* PL = ws + offBIG;
    float* PR = PL + (size_t)NNODE*NN;
    float* out = (float*)d_out;

    k_init <<<dim3(NNODE), dim3(256), 0, stream>>>(in, len, H, Cc, LG, NXT, PRV, ROWS);
    k_descA<<<dim3(NNODE/256), dim3(256), 0, stream>>>(len, ROWSA, ROWSN);

    // phase A: per-node products + pair combine
    k_gemmP<8,32><<<dim3(NNODE/128, 2*NN/64), dim3(256), 0, stream>>>(ROWSN, H, W, PL, PR);
    k_combineP<<<dim3(AROWS), dim3(256), 0, stream>>>(ROWSA, PL, PR, Cc, bias, q, CH, CC, LG);

    // cooperative whole-loop kernel (step0 + 46 steps + output)
    void* args[] = {
        (void*)&len, (void*)&H, (void*)&Cc, (void*)&CH, (void*)&CC,
        (void*)&LG, (void*)&NXT, (void*)&PRV, (void*)&ROWS, (void*)&PROW,
        (void*)&PL, (void*)&PR, (void*)&W, (void*)&bias, (void*)&q, (void*)&out
    };
    hipError_t err = hipLaunchCooperativeKernel((void*)k_loop, dim3(LGRID), dim3(256),
                                                args, 0, stream);
    if (err != hipSuccess){
        // fallback: per-step launch loop
        k_step0<<<dim3(NB), dim3(64), 0, stream>>>(len, H, Cc, CH, CC, LG, NXT, PRV, ROWS, PROW);
        for (int i = 1; i < NL-1; ++i){
            k_gemmP<4,32><<<dim3(NB/64, 2*NN/64), dim3(256), 0, stream>>>(PROW, H, W, PL, PR);
            k_combineStep<<<dim3(NB), dim3(256), 0, stream>>>(
                i, len, PL, PR, ROWS, PROW, H, Cc, CH, CC, LG, NXT, PRV, bias, q);
        }
        k_out<<<dim3(NB), dim3(128), 0, stream>>>(H, out);
    }
}

// Round 6
// 1992.981 us; speedup vs baseline: 4.1158x; 4.1158x over previous
//
#include <hip/hip_runtime.h>
#include <cfloat>
#include <cmath>

#define NB 128
#define NL 48
#define HID 512
#define NSLOT 48
#define NN 2560              // 5*HID output cols
#define NNODE (NB*NSLOT)     // 6144
#define AROWS (NB*(NL-1))    // 6016 phase-A pair rows

// ---------------- workspace layout (float units) ----------------
static const size_t offH    = 0;                                   // [B][48][512]
static const size_t offC    = offH  + (size_t)NNODE*HID;
static const size_t offCH   = offC  + (size_t)NNODE*HID;           // candidate h
static const size_t offCC   = offCH + (size_t)NNODE*HID;           // candidate c
static const size_t offLG   = offCC + (size_t)NNODE*HID;           // logits [B][48]
static const size_t offNXT  = offLG  + NNODE;                      // int
static const size_t offPRV  = offNXT + NNODE;                      // int
static const size_t offROWS = offPRV + NNODE;                      // int4 x 256
static const size_t offROWSA= offROWS + (size_t)4*(2*NB);          // int4 x 6016
static const size_t offROWSN= offROWSA + (size_t)4*AROWS;          // int x 6144
static const size_t offPROW = offROWSN + NNODE;                    // int x 128
static const size_t offBIG  = offPROW + 128;                       // PL, PR (NNODE*NN each)

__device__ __forceinline__ float sigf(float x){ return 1.0f/(1.0f+expf(-x)); }

// ---------------- init: copy input -> H,C ; init links/logits ----------------
__global__ void k_init(const float* __restrict__ in, const int* __restrict__ len,
                       float* __restrict__ H, float* __restrict__ Cc,
                       float* __restrict__ LG, int* __restrict__ NXT,
                       int* __restrict__ PRV, int4* __restrict__ ROWS)
{
    int bs = blockIdx.x;            // b*48+s
    int b  = bs / NSLOT, s = bs % NSLOT;
    int t  = threadIdx.x;           // 256 threads, 1 float4 each
    const float4* inrow = (const float4*)(in + (size_t)bs*2*HID);
    float4 v = inrow[t];
    if (t < 128) ((float4*)(H  + (size_t)bs*HID))[t]       = v;
    else         ((float4*)(Cc + (size_t)bs*HID))[t - 128] = v;
    if (t == 0) {
        int lb = len[b];
        NXT[bs] = (s+1 < lb) ? s+1 : -1;
        PRV[bs] = (s > 0 && s < lb) ? s-1 : -1;
        LG[bs]  = -FLT_MAX;
        if (s == 0) {
            ROWS[b*2+0] = make_int4(0,0,0,-1);
            ROWS[b*2+1] = make_int4(0,0,0,-1);
        }
    }
}

// ---------------- descriptors: pair rows (phase A) + node rows ----------------
__global__ void k_descA(const int* __restrict__ len, int4* __restrict__ ROWSA,
                        int* __restrict__ ROWSN)
{
    int r = blockIdx.x*256 + threadIdx.x;
    if (r < NNODE) ROWSN[r] = r;
    if (r >= AROWS) return;
    int b = r/(NL-1), s = r%(NL-1);
    int lb = len[b];
    ROWSA[r] = make_int4(b, s, s+1, (s <= lb-2) ? s : -1);
}

// ================= phase-A split-W product GEMM =================
// PL[node][n] = sum_k H[node][k]*W[n][k],  PR[node][n] = sum_k H[node][k]*W[n][512+k]
template<int MI, int KT>
__global__ __launch_bounds__(256, 4)
void k_gemmP(const int* __restrict__ rows,
             const float* __restrict__ H, const float* __restrict__ W,
             float* __restrict__ PL, float* __restrict__ PR)
{
    constexpr int BM  = 16*MI;
    constexpr int AF4 = BM/64;
    constexpr int LDA = BM + 4;
    constexpr int LDB = 68;
    __shared__ float As[2][16*LDA];
    __shared__ float Bs[2][16*LDB];

    const int t   = threadIdx.x;
    const int m0  = blockIdx.x*BM;
    const int vn0 = blockIdx.y*64;
    const int side = (vn0 >= NN);
    const int n0  = side ? vn0 - NN : vn0;
    float* OUT = side ? PR : PL;

    int aoff[AF4], arow[AF4], aseg[AF4];
    #pragma unroll
    for (int j=0;j<AF4;++j){
        int f = t*AF4 + j;
        arow[j] = f >> 2; aseg[j] = f & 3;
        aoff[j] = rows[m0 + arow[j]]*HID + aseg[j]*4;
    }
    const int brow = t >> 2, bseg = t & 3;
    const float* wptr = W + (size_t)(n0 + brow)*1024 + side*HID + bseg*4;

    const int tm = t >> 4, tn = t & 15;

    float acc[MI][4];
    #pragma unroll
    for (int mi=0;mi<MI;++mi)
        #pragma unroll
        for (int j=0;j<4;++j) acc[mi][j]=0.f;

    float4 av[AF4], bv;
    auto gload = [&](int kt){
        int kg = kt*16;
        #pragma unroll
        for (int j=0;j<AF4;++j) av[j] = *(const float4*)(H + aoff[j] + kg);
        bv = *(const float4*)(wptr + kg);
    };
    auto swrite = [&](int buf){
        #pragma unroll
        for (int j=0;j<AF4;++j){
            As[buf][(aseg[j]*4+0)*LDA + arow[j]] = av[j].x;
            As[buf][(aseg[j]*4+1)*LDA + arow[j]] = av[j].y;
            As[buf][(aseg[j]*4+2)*LDA + arow[j]] = av[j].z;
            As[buf][(aseg[j]*4+3)*LDA + arow[j]] = av[j].w;
        }
        Bs[buf][(bseg*4+0)*LDB + brow] = bv.x;
        Bs[buf][(bseg*4+1)*LDB + brow] = bv.y;
        Bs[buf][(bseg*4+2)*LDB + brow] = bv.z;
        Bs[buf][(bseg*4+3)*LDB + brow] = bv.w;
    };

    gload(0); swrite(0); __syncthreads();

    for (int kt=0; kt<KT; ++kt){
        int buf = kt & 1;
        if (kt+1 < KT) gload(kt+1);
        #pragma unroll
        for (int k=0;k<16;++k){
            float a[MI];
            #pragma unroll
            for (int mi=0;mi<MI;mi+=4){
                float4 a4 = *(const float4*)&As[buf][k*LDA + tm*MI + mi];
                a[mi]=a4.x; a[mi+1]=a4.y; a[mi+2]=a4.z; a[mi+3]=a4.w;
            }
            float4 b4 = *(const float4*)&Bs[buf][k*LDB + tn*4];
            #pragma unroll
            for (int mi=0;mi<MI;++mi){
                acc[mi][0] = fmaf(a[mi], b4.x, acc[mi][0]);
                acc[mi][1] = fmaf(a[mi], b4.y, acc[mi][1]);
                acc[mi][2] = fmaf(a[mi], b4.z, acc[mi][2]);
                acc[mi][3] = fmaf(a[mi], b4.w, acc[mi][3]);
            }
        }
        if (kt+1 < KT) swrite(buf^1);
        __syncthreads();
    }

    #pragma unroll
    for (int mi=0;mi<MI;++mi){
        int row = m0 + tm*MI + mi;
        float4 o; o.x=acc[mi][0]; o.y=acc[mi][1]; o.z=acc[mi][2]; o.w=acc[mi][3];
        *(float4*)(OUT + (size_t)rows[row]*NN + n0 + tn*4) = o;
    }
}

// ================= per-step GEMM: XCD-pinned, M=128 (new nodes) =================
// grid = 320 linear blocks. xcd = bid&7 owns a fixed 10-vn-tile W slice (1.31MB, L2-hot).
// BM=32, BN=64, 2x4 micro, K=512 in one pass. Direct write to PL/PR.
__global__ __launch_bounds__(256, 4)
void k_gemmS(const int* __restrict__ rows,
             const float* __restrict__ H, const float* __restrict__ W,
             float* __restrict__ PL, float* __restrict__ PR)
{
    constexpr int LDA = 36;
    constexpr int LDB = 68;
    __shared__ float As[2][16*LDA];
    __shared__ float Bs[2][16*LDB];

    const int bid = blockIdx.x;
    const int xcd = bid & 7;
    const int j   = bid >> 3;          // 0..39
    const int vnt = xcd*10 + (j % 10); // 0..79 : stable vn tile per XCD
    const int m0  = (j / 10) * 32;     // 0,32,64,96
    const int side = (vnt >= 40);
    const int n0  = (vnt - side*40)*64;
    float* OUT = side ? PR : PL;

    const int t = threadIdx.x;

    // A staging: threads 0..127 load 1 float4 (32 rows x 16 k)
    const int arow = (t & 127) >> 2, aseg = t & 3;
    const float* aptr = H + (size_t)rows[m0 + arow]*HID + aseg*4;
    // B staging: all 256 threads load 1 float4 (64 rows x 16 k)
    const int brow = t >> 2, bseg = t & 3;
    const float* bptr = W + (size_t)(n0 + brow)*1024 + side*HID + bseg*4;

    const int tm = t >> 4, tn = t & 15;   // rows tm*2, cols tn*4

    float acc[2][4];
    #pragma unroll
    for (int mi=0;mi<2;++mi)
        #pragma unroll
        for (int jj=0;jj<4;++jj) acc[mi][jj]=0.f;

    float4 av, bv;
    auto gload = [&](int kt){
        if (t < 128) av = *(const float4*)(aptr + kt*16);
        bv = *(const float4*)(bptr + kt*16);
    };
    auto swrite = [&](int buf){
        if (t < 128){
            As[buf][(aseg*4+0)*LDA + arow] = av.x;
            As[buf][(aseg*4+1)*LDA + arow] = av.y;
            As[buf][(aseg*4+2)*LDA + arow] = av.z;
            As[buf][(aseg*4+3)*LDA + arow] = av.w;
        }
        Bs[buf][(bseg*4+0)*LDB + brow] = bv.x;
        Bs[buf][(bseg*4+1)*LDB + brow] = bv.y;
        Bs[buf][(bseg*4+2)*LDB + brow] = bv.z;
        Bs[buf][(bseg*4+3)*LDB + brow] = bv.w;
    };

    gload(0); swrite(0); __syncthreads();

    for (int kt=0; kt<32; ++kt){
        int buf = kt & 1;
        if (kt+1 < 32) gload(kt+1);
        #pragma unroll
        for (int k=0;k<16;++k){
            float2 a2 = *(const float2*)&As[buf][k*LDA + tm*2];
            float4 b4 = *(const float4*)&Bs[buf][k*LDB + tn*4];
            acc[0][0] = fmaf(a2.x, b4.x, acc[0][0]);
            acc[0][1] = fmaf(a2.x, b4.y, acc[0][1]);
            acc[0][2] = fmaf(a2.x, b4.z, acc[0][2]);
            acc[0][3] = fmaf(a2.x, b4.w, acc[0][3]);
            acc[1][0] = fmaf(a2.y, b4.x, acc[1][0]);
            acc[1][1] = fmaf(a2.y, b4.y, acc[1][1]);
            acc[1][2] = fmaf(a2.y, b4.z, acc[1][2]);
            acc[1][3] = fmaf(a2.y, b4.w, acc[1][3]);
        }
        if (kt+1 < 32) swrite(buf^1);
        __syncthreads();
    }

    #pragma unroll
    for (int mi=0;mi<2;++mi){
        int node = rows[m0 + tm*2 + mi];
        float4 o; o.x=acc[mi][0]; o.y=acc[mi][1]; o.z=acc[mi][2]; o.w=acc[mi][3];
        *(float4*)(OUT + (size_t)node*NN + n0 + tn*4) = o;
    }
}

// ---------------- phase-A combine: v = PL[l]+PR[r]+bias -> gates -> CH/CC + logit ----------------
__global__ void k_combineP(const int4* __restrict__ rows,
                           const float* __restrict__ PL, const float* __restrict__ PR,
                           const float* __restrict__ Cc, const float* __restrict__ bias,
                           const float* __restrict__ q,
                           float* __restrict__ CH, float* __restrict__ CC,
                           float* __restrict__ LG)
{
    int4 rd = rows[blockIdx.x];
    if (rd.w < 0) return;
    int t = threadIdx.x;
    int b = rd.x, sl = rd.y, sr = rd.z, dst = rd.w;
    const float* pl = PL + (size_t)(b*NSLOT+sl)*NN;
    const float* pr = PR + (size_t)(b*NSLOT+sr)*NN;
    const float* cl = Cc + (size_t)(b*NSLOT+sl)*HID;
    const float* cr = Cc + (size_t)(b*NSLOT+sr)*HID;
    float part = 0.f;
    #pragma unroll
    for (int h2=0; h2<2; ++h2){
        int c = t + h2*256;
        float v[5];
        #pragma unroll
        for (int g=0; g<5; ++g)
            v[g] = pl[g*HID+c] + pr[g*HID+c] + bias[g*HID+c];
        float cn = cl[c]*sigf(v[1]+1.f) + cr[c]*sigf(v[2]+1.f) + tanhf(v[3])*sigf(v[0]);
        float hn = sigf(v[4])*tanhf(cn);
        CH[(size_t)(b*NSLOT+dst)*HID + c] = hn;
        CC[(size_t)(b*NSLOT+dst)*HID + c] = cn;
        part += q[c]*hn;
    }
    __shared__ float red[4];
    #pragma unroll
    for (int off=32; off; off>>=1) part += __shfl_xor(part, off);
    if ((t & 63) == 0) red[t>>6] = part;
    __syncthreads();
    if (t == 0) LG[b*NSLOT + dst] = red[0]+red[1]+red[2]+red[3];
}

// ---------------- step 0: argmax, commit, relink (phase-A logits) ----------------
__global__ void k_step0(const int* __restrict__ len,
                        float* __restrict__ H, float* __restrict__ Cc,
                        const float* __restrict__ CH, const float* __restrict__ CC,
                        float* __restrict__ LG, int* __restrict__ NXT,
                        int* __restrict__ PRV, int4* __restrict__ ROWS,
                        int* __restrict__ PROW)
{
    int b = blockIdx.x, lane = threadIdx.x;   // block = 64 = 1 wave
    int base = b*NSLOT;

    float val = (lane < NSLOT) ? LG[base+lane] : -FLT_MAX;
    int idx = lane;
    for (int off=1; off<64; off<<=1){
        float oval = __shfl_xor(val, off);
        int   oidx = __shfl_xor(idx, off);
        if (oval > val || (oval == val && oidx < idx)){ val = oval; idx = oidx; }
    }
    int sstar = idx;
    int r  = NXT[base+sstar];
    int qn = NXT[base+r];
    int p  = PRV[base+sstar];

    const float4* sh = (const float4*)(CH + (size_t)(base+sstar)*HID);
    const float4* sc = (const float4*)(CC + (size_t)(base+sstar)*HID);
    float4* dh = (float4*)(H  + (size_t)(base+sstar)*HID);
    float4* dc = (float4*)(Cc + (size_t)(base+sstar)*HID);
    dh[lane] = sh[lane]; dh[lane+64] = sh[lane+64];
    dc[lane] = sc[lane]; dc[lane+64] = sc[lane+64];

    if (lane==0){
        NXT[base+sstar] = qn;
        if (qn >= 0) PRV[base+qn] = sstar;
        LG[base+r] = -FLT_MAX;
        if (qn < 0) LG[base+sstar] = -FLT_MAX;
        ROWS[b*2+0] = (p  >= 0) ? make_int4(b, p, sstar, p)      : make_int4(0,0,0,-1);
        ROWS[b*2+1] = (qn >= 0) ? make_int4(b, sstar, qn, sstar) : make_int4(0,0,0,-1);
        PROW[b] = base + sstar;
    }
}

// ---------------- fused: finish 2 pairs + argmax + commit + relink ----------------
__global__ __launch_bounds__(256, 4)
void k_combineStep(int i, const int* __restrict__ len,
                   const float* __restrict__ PL, const float* __restrict__ PR,
                   int4* __restrict__ ROWS, int* __restrict__ PROW,
                   float* __restrict__ H, float* __restrict__ Cc,
                   float* __restrict__ CH, float* __restrict__ CC,
                   float* __restrict__ LG, int* __restrict__ NXT,
                   int* __restrict__ PRV,
                   const float* __restrict__ bias, const float* __restrict__ q)
{
    int b = blockIdx.x, t = threadIdx.x;
    int base = b*NSLOT;
    int4 r0 = ROWS[b*2+0], r1 = ROWS[b*2+1];
    bool v0 = (r0.w >= 0), v1 = (r1.w >= 0);
    int node = PROW[b];
    __shared__ float slg[NSLOT];
    __shared__ float red[8];
    __shared__ int ss[1];

    float plnew[10], prnew[10];
    if (v0 || v1){
        #pragma unroll
        for (int jj=0;jj<10;++jj){
            int c = jj*256 + t;
            plnew[jj] = PL[(size_t)node*NN + c];
            prnew[jj] = PR[(size_t)node*NN + c];
        }
    }
    for (int e=0; e<2; ++e){
        int4 rd = e ? r1 : r0;
        bool valid = e ? v1 : v0;
        float part = 0.f;
        if (valid){
            const float* OTH = e ? (PR + (size_t)(base+rd.z)*NN)
                                 : (PL + (size_t)(base+rd.y)*NN);
            const float* cl = Cc + (size_t)(base+rd.y)*HID;
            const float* cr = Cc + (size_t)(base+rd.z)*HID;
            int dst = rd.w;
            #pragma unroll
            for (int h2=0; h2<2; ++h2){
                int c = t + h2*256;
                float v[5];
                #pragma unroll
                for (int g=0; g<5; ++g){
                    int jj = g*2 + h2;
                    float mine = e ? plnew[jj] : prnew[jj];
                    v[g] = OTH[g*HID + c] + mine + bias[g*HID + c];
                }
                float cn = cl[c]*sigf(v[1]+1.f) + cr[c]*sigf(v[2]+1.f) + tanhf(v[3])*sigf(v[0]);
                float hn = sigf(v[4])*tanhf(cn);
                CH[(size_t)(base+dst)*HID + c] = hn;
                CC[(size_t)(base+dst)*HID + c] = cn;
                part += q[c]*hn;
            }
        }
        #pragma unroll
        for (int off=32; off; off>>=1) part += __shfl_xor(part, off);
        if ((t & 63) == 0) red[e*4 + (t>>6)] = part;
    }
    if (t < NSLOT) slg[t] = LG[base+t];
    __syncthreads();
    if (t == 0){
        float s0 = red[0]+red[1]+red[2]+red[3];
        float s1 = red[4]+red[5]+red[6]+red[7];
        if (v0){ LG[base+r0.w]=s0; slg[r0.w]=s0; }
        if (v1){ LG[base+r1.w]=s1; slg[r1.w]=s1; }
    }
    __syncthreads();

    int lb = len[b];
    if (i > lb-2){
        if (t==0){
            ROWS[b*2+0]=make_int4(0,0,0,-1);
            ROWS[b*2+1]=make_int4(0,0,0,-1);
            PROW[b]=base;
        }
        return;
    }

    if (t < 64){
        float val = (t < NSLOT)? slg[t] : -FLT_MAX;
        int idx = t;
        for (int off=1; off<64; off<<=1){
            float ov=__shfl_xor(val,off); int oi=__shfl_xor(idx,off);
            if (ov>val || (ov==val && oi<idx)){ val=ov; idx=oi; }
        }
        if (t==0) ss[0]=idx;
    }
    __syncthreads();
    int sstar = ss[0];
    {
        const float4* sh = (const float4*)(CH + (size_t)(base+sstar)*HID);
        const float4* sc = (const float4*)(CC + (size_t)(base+sstar)*HID);
        float4* dh = (float4*)(H  + (size_t)(base+sstar)*HID);
        float4* dc = (float4*)(Cc + (size_t)(base+sstar)*HID);
        if (t < 128) dh[t] = sh[t];
        else         dc[t-128] = sc[t-128];
    }
    if (t == 0){
        int r  = NXT[base+sstar];
        int qn = NXT[base+r];
        int p  = PRV[base+sstar];
        NXT[base+sstar] = qn;
        if (qn >= 0) PRV[base+qn] = sstar;
        LG[base+r] = -FLT_MAX;
        if (qn < 0) LG[base+sstar] = -FLT_MAX;
        ROWS[b*2+0] = (p  >= 0) ? make_int4(b, p, sstar, p)      : make_int4(0,0,0,-1);
        ROWS[b*2+1] = (qn >= 0) ? make_int4(b, sstar, qn, sstar) : make_int4(0,0,0,-1);
        PROW[b] = base + sstar;
    }
}

// ---------------- output: root = slot 0 ----------------
__global__ void k_out(const float* __restrict__ H, float* __restrict__ out)
{
    int b = blockIdx.x, t = threadIdx.x;       // 128 threads x float4
    ((float4*)out)[b*128 + t] = ((const float4*)(H + (size_t)b*NSLOT*HID))[t];
}

extern "C" void kernel_launch(void* const* d_in, const int* in_sizes, int n_in,
                              void* d_out, int out_size, void* d_ws, size_t ws_size,
                              hipStream_t stream)
{
    const float* in   = (const float*)d_in[0];
    const float* W    = (const float*)d_in[1];
    const float* bias = (const float*)d_in[2];
    const float* q    = (const float*)d_in[3];
    const int*   len  = (const int*)d_in[4];

    float* ws = (float*)d_ws;
    float* H  = ws + offH;
    float* Cc = ws + offC;
    float* CH = ws + offCH;
    float* CC = ws + offCC;
    float* LG = ws + offLG;
    int* NXT  = (int*)(ws + offNXT);
    int* PRV  = (int*)(ws + offPRV);
    int4* ROWS  = (int4*)(ws + offROWS);
    int4* ROWSA = (int4*)(ws + offROWSA);
    int*  ROWSN = (int*)(ws + offROWSN);
    int*  PROW  = (int*)(ws + offPROW);
    float* PL = ws + offBIG;
    float* PR = PL + (size_t)NNODE*NN;
    float* out = (float*)d_out;

    k_init <<<dim3(NNODE), dim3(256), 0, stream>>>(in, len, H, Cc, LG, NXT, PRV, ROWS);
    k_descA<<<dim3(NNODE/256), dim3(256), 0, stream>>>(len, ROWSA, ROWSN);

    // phase A: per-node products + pair combine + first merge
    k_gemmP<8,32><<<dim3(NNODE/128, 2*NN/64), dim3(256), 0, stream>>>(ROWSN, H, W, PL, PR);
    k_combineP<<<dim3(AROWS), dim3(256), 0, stream>>>(ROWSA, PL, PR, Cc, bias, q, CH, CC, LG);
    k_step0<<<dim3(NB), dim3(64), 0, stream>>>(len, H, Cc, CH, CC, LG, NXT, PRV, ROWS, PROW);

    // step loop: 2 kernels per iteration
    for (int i = 1; i < NL-1; ++i){
        k_gemmS<<<dim3(320), dim3(256), 0, stream>>>(PROW, H, W, PL, PR);
        k_combineStep<<<dim3(NB), dim3(256), 0, stream>>>(
            i, len, PL, PR, ROWS, PROW, H, Cc, CH, CC, LG, NXT, PRV, bias, q);
    }
    k_out<<<dim3(NB), dim3(128), 0, stream>>>(H, out);
}